// Round 7
// baseline (253.686 us; speedup 1.0000x reference)
//
#include <hip/hip_runtime.h>

#define HH 384
#define WW 384
#define OUTD 370
#define NSHIFT 99

// ---- R21: packed-f32 (v_pk_*_f32) over the P/G image pair ----
// Ledger: R16 occ x1.33 -> 0; R17 barriers /2 -> 0; R18 relayout -> -19%;
// R19 sw-pipe -> -7%; R20 DS-instrs /2 -> 0 (its 2.4e7 conflicts = benign
// 2-way, m136). Only unvaried quantity: VALU instr count, and VALUBusy ~95
// is consistently high -> kernel is VALU-ISSUE-bound. Fix: pack images P,G
// as f32x2 (ext_vector_type -> <2 x float> -> v_pk_fma/add/mul_f32, CDNA
// full-rate dual-f32). Every conv instruction now does both images: conv
// VALU halves, DS instrs halve (b64). R6/R14's packed failure (pack movs +
// strided reads) is structurally avoided: packing happens ONCE in load_tile;
// layout natural thereafter. Per-element math + ascending-s order identical
// -> absmax 0 preserved.
// Geometry: R13 core (32x24 tile, 187us proven). horiz = 240 quad-units
// (30 rows x 8 col-quads, tid<240, 4 outputs each); vert = 256 units
// (32 cols x 8 strips of 3 rows), packed pair per thread -> loss |ep-eg|
// computed in-thread (no lane exchange).
// Banks (b64: each lane = 1 bank-pair, 32 lanes -> 16 pairs x2 = minimum):
//  horiz reads  : dword (30*hr + 8*hq) mod 32 -> 16 distinct pairs x2 ✓
//  horiz writes : (12*hq + hr + 15k) mod 16  -> all 16 pairs x2 ✓
//  vert reads   : (-2*vx) mod 32             -> 16 distinct pairs x2 ✓
#define TW 32
#define TH 24
#define LSTR2 47          // L stride in f32x2
#define LROWS 39          // 24 + 6 conv + 9 shift span
#define LSZ (LROWS * LSTR2)   // 1833 f32x2
#define TMS2 31           // transposed tmp stride in f32x2 (== -1 mod 16)
#define TTSZ2 (TW * TMS2) // 992 f32x2
#define NXT 12
#define NYT 16

#define G0 0.32465246735834974f   // exp(-9/8)
#define G1 0.6065306597126334f    // exp(-4/8)
#define G2 0.8824969025845955f    // exp(-1/8)
#define KS 0.039788735772973836f  // 1/(8*pi)
#define LOG2E 1.4426950408889634f

typedef __attribute__((ext_vector_type(2))) float f32x2;

__device__ __forceinline__ f32x2 tap7p(const f32x2* v)
{
    const f32x2 g0 = (f32x2)(G0), g1 = (f32x2)(G1), g2 = (f32x2)(G2);
    return __builtin_elementwise_fma(g0, v[0] + v[6],
           __builtin_elementwise_fma(g1, v[1] + v[5],
           __builtin_elementwise_fma(g2, v[2] + v[4], v[3])));
}

__device__ __forceinline__ void shift_of(int s, int& sx, int& sy)
{
    int t = (s < 55) ? s : s + 1;    // skip (0,0)
    sx = t / 10 - 5;
    sy = t - (t / 10) * 10 - 5;
}

__device__ __forceinline__ void load_tile2(const float* __restrict__ pr,
                                           const float* __restrict__ gt,
                                           int oy0, int ox0, f32x2* L, int tid)
{
    for (int i = tid; i < LSZ; i += 256) {
        int r = i / LSTR2, c = i - r * LSTR2;
        int gr = oy0 + r; if (gr >= HH) gr -= HH;   // circular wrap
        int gc = ox0 + c; if (gc >= WW) gc -= WW;
        f32x2 t;
        t.x = pr[gr * WW + gc];
        t.y = gt[gr * WW + gc];
        L[i] = t;
    }
}

// horizontal 7-tap over inline diff^2, both images packed; 4 outputs -> transposed tmp
__device__ __forceinline__ void horiz4(const f32x2* __restrict__ Lb,
                                       const f32x2* __restrict__ cA,
                                       f32x2* __restrict__ tb,
                                       int r, int c0, int sx, int sy)
{
    const f32x2* Ls = &Lb[(r + 4 - sy) * LSTR2 + (c0 + 4 - sx)];
    f32x2 v[10];
#pragma unroll
    for (int t = 0; t < 10; ++t) { f32x2 d = cA[t] - Ls[t]; v[t] = d * d; }
#pragma unroll
    for (int k = 0; k < 4; ++k) tb[(c0 + k) * TMS2 + r] = tap7p(v + k);
}

// vertical 7-tap, 3 packed outputs from 9 consecutive tmp values
__device__ __forceinline__ void vert3p(const f32x2* __restrict__ tT,
                                       int vx, int vy0, f32x2* D)
{
    const f32x2* t = &tT[vx * TMS2 + vy0];
    f32x2 w[9];
#pragma unroll
    for (int j = 0; j < 9; ++j) w[j] = t[j];
    const f32x2 ks = (f32x2)(KS);
#pragma unroll
    for (int k = 0; k < 3; ++k) D[k] = ks * tap7p(w + k);
}

extern "C" __global__ void __launch_bounds__(256, 3)
mind_fused(const float* __restrict__ pred, const float* __restrict__ gt,
           float* __restrict__ out)
{
    __shared__ f32x2 L2[LSZ];
    __shared__ f32x2 tT2[2][TTSZ2];
    __shared__ float wred[4];
    const int tid = threadIdx.x;
    const int b = blockIdx.y;
    const int oy0 = ((int)blockIdx.x / NXT) * TH;
    const int ox0 = ((int)blockIdx.x % NXT) * TW;

    load_tile2(pred + (size_t)b * HH * WW, gt + (size_t)b * HH * WW,
               oy0, ox0, L2, tid);

    // horiz: 240 units = 30 rows x 8 col-quads, tid 0..239
    const bool hasH = tid < 240;
    const int hr = tid >> 3, hq = tid & 7, hc0 = hq << 2;

    // vert: 256 units = 32 cols x 8 strips of 3 rows, both images packed
    const int vx = tid & 31, vy0 = (tid >> 5) * 3;

    __syncthreads();

    f32x2 cA[10];
    if (hasH) {
        const f32x2* p = &L2[(hr + 4) * LSTR2 + hc0 + 4];
#pragma unroll
        for (int t = 0; t < 10; ++t) cA[t] = p[t];
    }

    // ---- phase 1: V (4 cardinals) and minD over 99 shifts, packed ----
    f32x2 dm[3], vs[3];
#pragma unroll
    for (int k = 0; k < 3; ++k) { dm[k] = (f32x2)(1e30f); vs[k] = (f32x2)(0.f); }

    for (int s = 0; s < NSHIFT; ++s) {
        int sx, sy; shift_of(s, sx, sy);
        if (hasH) horiz4(L2, cA, tT2[s & 1], hr, hc0, sx, sy);
        __syncthreads();   // tT2[s&1] ready; parity alternation -> WAR safe
        f32x2 D[3];
        vert3p(tT2[s & 1], vx, vy0, D);
        const bool card = (sx * sx + sy * sy) == 1;
#pragma unroll
        for (int k = 0; k < 3; ++k) {
            dm[k] = __builtin_elementwise_min(dm[k], D[k]);
            if (card) vs[k] += D[k];
        }
    }

    // loss constants; invalid pixels get rv=0 -> ep=eg=exp2(0)=1 -> |ep-eg|=0
    float rvp[3], rvg[3];
#pragma unroll
    for (int k = 0; k < 3; ++k) {
        int oy = oy0 + vy0 + k, ox = ox0 + vx;
        const bool valid = (oy < OUTD) && (ox < OUTD);
        rvp[k] = valid ? LOG2E / (vs[k].x * 0.25f + 1e-5f) : 0.f;
        rvg[k] = valid ? LOG2E / (vs[k].y * 0.25f + 1e-5f) : 0.f;
    }

    __syncthreads();   // phase boundary: protect buf-0 reuse against last vert read

    // ---- phase 2: recompute D, accumulate |exp2((m-D)*rv)p - (...)g| ----
    float acc = 0.f;
    for (int s = 0; s < NSHIFT; ++s) {
        int sx, sy; shift_of(s, sx, sy);
        if (hasH) horiz4(L2, cA, tT2[s & 1], hr, hc0, sx, sy);
        __syncthreads();
        f32x2 D[3];
        vert3p(tT2[s & 1], vx, vy0, D);
#pragma unroll
        for (int k = 0; k < 3; ++k) {
            float ep = exp2f((dm[k].x - D[k].x) * rvp[k]);
            float eg = exp2f((dm[k].y - D[k].y) * rvg[k]);
            acc += fabsf(ep - eg);
        }
    }

#pragma unroll
    for (int off = 32; off > 0; off >>= 1) acc += __shfl_down(acc, off, 64);
    const int lane = tid & 63, wv = tid >> 6;
    if (lane == 0) wred[wv] = acc;
    __syncthreads();
    if (tid == 0) {
        const float SC = (float)(1.0 / 54212400.0);  // 1/(4*370*370*99)
        atomicAdd(out, (wred[0] + wred[1] + wred[2] + wred[3]) * SC);
    }
}

extern "C" void kernel_launch(void* const* d_in, const int* in_sizes, int n_in,
                              void* d_out, int out_size, void* d_ws, size_t ws_size,
                              hipStream_t stream)
{
    (void)in_sizes; (void)n_in; (void)out_size; (void)d_ws; (void)ws_size;
    const float* pred = (const float*)d_in[0];
    const float* gt   = (const float*)d_in[1];
    float* out = (float*)d_out;

    hipMemsetAsync(d_out, 0, sizeof(float), stream);

    dim3 g(NXT * NYT, 4, 1);   // 192 tiles x 4 batch = 768 blocks = 3/CU exact
    mind_fused<<<g, 256, 0, stream>>>(pred, gt, out);
}

// Round 8
// 250.703 us; speedup vs baseline: 1.0119x; 1.0119x over previous
//
#include <hip/hip_runtime.h>

#define HH 384
#define WW 384
#define OUTD 370
#define NSHIFT 99

// ---- R22: packed-f32 horiz core on the R13 DS skeleton ----
// Ledger: R16 occ x1.33 -> 0; R17 barriers /2 -> 0; R18 relayout -> -19%;
// R19 sw-pipe -> -7%; R20 DS /2 -> 0; R21 VALU /2 (VALUBusy 95->54, pk
// codegen CONFIRMED) -> -18% because its strided-b64 tmp/vert moved DS into
// the conflict regime (3.2e7 cy). Unified model: R13 is VALU-ISSUE-bound at
// ~94% REAL busy (~357 wave-instr/wave-iter incl. addressing overhead);
// DS must stay in R13's proven cheap regime (b32, conflict-free, merges).
// R22: interleave P,G as f32x2 in ONE L tile; horiz = 120 octet-units doing
// BOTH images via v_pk_fma_f32 (core math halves, zero pack-assembly since
// loads are naturally paired); outputs extracted (.x/.y, free sub-reg) into
// the two SEPARATE b32 tmp planes with R13's stride-31 writes.
// Write bank law (per 32-lane phase, 8 rows x 4 quads): dword residue
// hr - 8*hq - k mod 32 bijective -> 0 conflict. Horiz packed reads: row
// stride 94 dwords -> 2-way even-bank aliasing only (free per m136).
// Vert + loss + order: R13 verbatim -> absmax 0 preserved.
#define TW 32
#define TH 24
#define LSTR2 47          // L stride in f32x2 cells (row geometry as R13)
#define LROWS 39          // 24 + 6 conv + 9 shift span
#define LPAD2 1840        // 39*47=1833 padded -> tmp bases 32-dword aligned
#define TMS 31            // tmp_T stride (==-1 mod 32, R13-proven)
#define TTSZ (TW * TMS)   // 992 dwords
#define NXT 12
#define NYT 16

#define G0 0.32465246735834974f   // exp(-9/8)
#define G1 0.6065306597126334f    // exp(-4/8)
#define G2 0.8824969025845955f    // exp(-1/8)
#define KS 0.039788735772973836f  // 1/(8*pi)
#define LOG2E 1.4426950408889634f

typedef __attribute__((ext_vector_type(2))) float f32x2;

__device__ __forceinline__ float tap7(const float* v)
{
    return fmaf(G0, v[0] + v[6],
           fmaf(G1, v[1] + v[5],
           fmaf(G2, v[2] + v[4], v[3])));
}

__device__ __forceinline__ f32x2 tap7p(const f32x2* v)
{
    const f32x2 g0 = (f32x2)(G0), g1 = (f32x2)(G1), g2 = (f32x2)(G2);
    return __builtin_elementwise_fma(g0, v[0] + v[6],
           __builtin_elementwise_fma(g1, v[1] + v[5],
           __builtin_elementwise_fma(g2, v[2] + v[4], v[3])));
}

__device__ __forceinline__ void shift_of(int s, int& sx, int& sy)
{
    int t = (s < 55) ? s : s + 1;    // skip (0,0)
    sx = t / 10 - 5;
    sy = t - (t / 10) * 10 - 5;
}

__device__ __forceinline__ void load_tile2(const float* __restrict__ pr,
                                           const float* __restrict__ gt,
                                           int oy0, int ox0, f32x2* L, int tid)
{
    for (int i = tid; i < LROWS * LSTR2; i += 256) {
        int r = i / LSTR2, c = i - r * LSTR2;
        int gr = oy0 + r; if (gr >= HH) gr -= HH;   // circular wrap
        int gc = ox0 + c; if (gc >= WW) gc -= WW;
        f32x2 t;
        t.x = pr[gr * WW + gc];
        t.y = gt[gr * WW + gc];
        L[i] = t;
    }
}

// horizontal 7-tap over inline diff^2, BOTH images packed; 8 packed outputs
// extracted into the two b32 transposed tmp planes (R13 write pattern).
__device__ __forceinline__ void horiz8p(const f32x2* __restrict__ Lb,
                                        const f32x2* __restrict__ cA,
                                        float* __restrict__ tbP,
                                        float* __restrict__ tbG,
                                        int r, int c0, int sx, int sy)
{
    const f32x2* Ls = &Lb[(r + 4 - sy) * LSTR2 + (c0 + 4 - sx)];
    f32x2 v[14];
#pragma unroll
    for (int t = 0; t < 14; ++t) { f32x2 d = cA[t] - Ls[t]; v[t] = d * d; }
    float* oP = &tbP[c0 * TMS + r];
    float* oG = &tbG[c0 * TMS + r];
#pragma unroll
    for (int k = 0; k < 8; ++k) {
        f32x2 o = tap7p(v + k);
        oP[k * TMS] = o.x;
        oG[k * TMS] = o.y;
    }
}

// vertical 7-tap, 3 outputs from 9 consecutive tmp_T values (R13 scalar core)
__device__ __forceinline__ void vert3(const float* __restrict__ tT, int vx, int vy0, float* D)
{
    const float* t = &tT[vx * TMS + vy0];
    float w[9];
#pragma unroll
    for (int j = 0; j < 9; ++j) w[j] = t[j];
#pragma unroll
    for (int k = 0; k < 3; ++k) D[k] = KS * tap7(w + k);
}

extern "C" __global__ void __launch_bounds__(256, 3)
mind_fused(const float* __restrict__ pred, const float* __restrict__ gt,
           float* __restrict__ out)
{
    __shared__ f32x2 L2[LPAD2];
    __shared__ float tTP[2][TTSZ];
    __shared__ float tTG[2][TTSZ];
    __shared__ float wred[4];
    const int tid = threadIdx.x;
    const int b = blockIdx.y;
    const int oy0 = ((int)blockIdx.x / NXT) * TH;
    const int ox0 = ((int)blockIdx.x % NXT) * TW;

    load_tile2(pred + (size_t)b * HH * WW, gt + (size_t)b * HH * WW,
               oy0, ox0, L2, tid);

    // horiz: 120 packed units = 30 rows x 4 col-octets, each does BOTH images
    const bool hasH = tid < 120;
    const int hr = tid >> 2, hc0 = (tid & 3) << 3;

    // vert: all 256 = 32 cols x 8 strips of 3 rows, both images per thread
    const int vx = tid & 31, vy0 = (tid >> 5) * 3;

    __syncthreads();

    f32x2 cA[14];
    if (hasH) {
        const f32x2* p = &L2[(hr + 4) * LSTR2 + hc0 + 4];
#pragma unroll
        for (int t = 0; t < 14; ++t) cA[t] = p[t];
    }

    // ---- phase 1: V (4 cardinals) and minD over 99 shifts, both images ----
    float dmp[3], vsp[3], dmg[3], vsg[3];
#pragma unroll
    for (int k = 0; k < 3; ++k) { dmp[k] = 1e30f; vsp[k] = 0.f; dmg[k] = 1e30f; vsg[k] = 0.f; }

    for (int s = 0; s < NSHIFT; ++s) {
        int sx, sy; shift_of(s, sx, sy);
        if (hasH) horiz8p(L2, cA, tTP[s & 1], tTG[s & 1], hr, hc0, sx, sy);
        __syncthreads();   // tmp[s&1] ready; parity alternation -> WAR safe
        float Dp[3], Dg[3];
        vert3(tTP[s & 1], vx, vy0, Dp);
        vert3(tTG[s & 1], vx, vy0, Dg);
        const bool card = (sx * sx + sy * sy) == 1;
#pragma unroll
        for (int k = 0; k < 3; ++k) {
            dmp[k] = fminf(dmp[k], Dp[k]);
            dmg[k] = fminf(dmg[k], Dg[k]);
            if (card) { vsp[k] += Dp[k]; vsg[k] += Dg[k]; }
        }
    }

    // loss constants; invalid pixels get rv=0 -> ep=eg=exp2(0)=1 -> |ep-eg|=0
    // exactly, so the phase-2 loop is fully branchless.
    float rvp[3], rvg[3];
#pragma unroll
    for (int k = 0; k < 3; ++k) {
        int oy = oy0 + vy0 + k, ox = ox0 + vx;
        const bool valid = (oy < OUTD) && (ox < OUTD);
        rvp[k] = valid ? LOG2E / (vsp[k] * 0.25f + 1e-5f) : 0.f;
        rvg[k] = valid ? LOG2E / (vsg[k] * 0.25f + 1e-5f) : 0.f;
    }

    __syncthreads();   // phase boundary: protect buf-0 reuse against last vert read

    // ---- phase 2: recompute D, accumulate |exp2((m-D)*rv)p - (...)g| ----
    float acc = 0.f;
    for (int s = 0; s < NSHIFT; ++s) {
        int sx, sy; shift_of(s, sx, sy);
        if (hasH) horiz8p(L2, cA, tTP[s & 1], tTG[s & 1], hr, hc0, sx, sy);
        __syncthreads();
        float Dp[3], Dg[3];
        vert3(tTP[s & 1], vx, vy0, Dp);
        vert3(tTG[s & 1], vx, vy0, Dg);
#pragma unroll
        for (int k = 0; k < 3; ++k) {
            float ep = exp2f((dmp[k] - Dp[k]) * rvp[k]);
            float eg = exp2f((dmg[k] - Dg[k]) * rvg[k]);
            acc += fabsf(ep - eg);
        }
    }

#pragma unroll
    for (int off = 32; off > 0; off >>= 1) acc += __shfl_down(acc, off, 64);
    const int lane = tid & 63, wv = tid >> 6;
    if (lane == 0) wred[wv] = acc;
    __syncthreads();
    if (tid == 0) {
        const float SC = (float)(1.0 / 54212400.0);  // 1/(4*370*370*99)
        atomicAdd(out, (wred[0] + wred[1] + wred[2] + wred[3]) * SC);
    }
}

extern "C" void kernel_launch(void* const* d_in, const int* in_sizes, int n_in,
                              void* d_out, int out_size, void* d_ws, size_t ws_size,
                              hipStream_t stream)
{
    (void)in_sizes; (void)n_in; (void)out_size; (void)d_ws; (void)ws_size;
    const float* pred = (const float*)d_in[0];
    const float* gt   = (const float*)d_in[1];
    float* out = (float*)d_out;

    hipMemsetAsync(d_out, 0, sizeof(float), stream);

    dim3 g(NXT * NYT, 4, 1);   // 192 tiles x 4 batch = 768 blocks = 3/CU exact
    mind_fused<<<g, 256, 0, stream>>>(pred, gt, out);
}